// Round 2
// baseline (316.677 us; speedup 1.0000x reference)
//
#include <hip/hip_runtime.h>
#include <hip/hip_bf16.h>
#include <stdint.h>

#define DIM 512
#define NROWS 1024
#define NCLS 70722
#define NCT2 277       // ceil(70722/256)

typedef float floatx4 __attribute__((ext_vector_type(4)));

// pack 4 floats -> 4 OCP e4m3 bytes (HW cvt, RNE+sat)
__device__ __forceinline__ unsigned pk4_fp8(float a, float b, float c, float d) {
    unsigned v = 0;
    v = __builtin_amdgcn_cvt_pk_fp8_f32(a, b, v, false);  // low 16 bits
    v = __builtin_amdgcn_cvt_pk_fp8_f32(c, d, v, true);   // high 16 bits
    return v;
}

__device__ __forceinline__ float wave_reduce_sum(float s) {
    #pragma unroll
    for (int m = 1; m < 64; m <<= 1) s += __shfl_xor(s, m);
    return s;
}

// --- kernel 1: fused prep ---------------------------------------------------
// blocks [0,256):    x rows -> fp8(16*x/||x||), rownorm, fp32 label cosine, rowsum=0
// blocks [256,...):  W rows -> fp8(16*w/||w||), wave-per-row fully coalesced
__global__ __launch_bounds__(256) void prep_kernel(
        const float* __restrict__ x, const float* __restrict__ W,
        const int* __restrict__ labels,
        uint8_t* __restrict__ An, uint8_t* __restrict__ Wn8,
        float* __restrict__ rownorm, float* __restrict__ coslab,
        float* __restrict__ rowsum) {
    int b = blockIdx.x;
    int wv = threadIdx.x >> 6, lane = threadIdx.x & 63;
    if (b < NROWS / 4) {
        if (threadIdx.x < 4) rowsum[b * 4 + threadIdx.x] = 0.0f;
        int row = b * 4 + wv;
        int lab = labels[row];
        const float4* xs = (const float4*)(x + (size_t)row * DIM);
        const float4* ws = (const float4*)(W + (size_t)lab * DIM);
        float4 xa = xs[lane * 2], xb = xs[lane * 2 + 1];
        float4 wa = ws[lane * 2], wb = ws[lane * 2 + 1];
        float dxx = xa.x*xa.x + xa.y*xa.y + xa.z*xa.z + xa.w*xa.w
                  + xb.x*xb.x + xb.y*xb.y + xb.z*xb.z + xb.w*xb.w;
        float dww = wa.x*wa.x + wa.y*wa.y + wa.z*wa.z + wa.w*wa.w
                  + wb.x*wb.x + wb.y*wb.y + wb.z*wb.z + wb.w*wb.w;
        float dxw = xa.x*wa.x + xa.y*wa.y + xa.z*wa.z + xa.w*wa.w
                  + xb.x*wb.x + xb.y*wb.y + xb.z*wb.z + xb.w*wb.w;
        dxx = wave_reduce_sum(dxx);
        dww = wave_reduce_sum(dww);
        dxw = wave_reduce_sum(dxw);
        float norm = sqrtf(dxx);
        float s16 = 16.0f / fmaxf(norm, 1e-12f);
        uint2 p;
        p.x = pk4_fp8(xa.x*s16, xa.y*s16, xa.z*s16, xa.w*s16);
        p.y = pk4_fp8(xb.x*s16, xb.y*s16, xb.z*s16, xb.w*s16);
        *(uint2*)(An + (size_t)row * DIM + lane * 8) = p;
        if (lane == 0) {
            rownorm[row] = norm;
            coslab[row]  = dxw / (fmaxf(norm, 1e-12f) * fmaxf(sqrtf(dww), 1e-12f));
        }
    } else {
        // wave-per-row: 64 lanes x 32B contiguous load, 512B contiguous store
        int c = (b - NROWS / 4) * 4 + wv;
        if (c < NCLS) {
            const float4* src = (const float4*)(W + (size_t)c * DIM);
            float4 va = src[lane * 2], vb = src[lane * 2 + 1];
            float ss = va.x*va.x + va.y*va.y + va.z*va.z + va.w*va.w
                     + vb.x*vb.x + vb.y*vb.y + vb.z*vb.z + vb.w*vb.w;
            ss = wave_reduce_sum(ss);
            float s16 = 16.0f / fmaxf(sqrtf(ss), 1e-12f);
            uint2 p;
            p.x = pk4_fp8(va.x*s16, va.y*s16, va.z*s16, va.w*s16);
            p.y = pk4_fp8(vb.x*s16, vb.y*s16, vb.z*s16, vb.w*s16);
            *(uint2*)(Wn8 + (size_t)c * DIM + lane * 8) = p;
        }
    }
}

// --- kernel 2: fp8 256x256 GEMM, BK=64, 4-phase/K-tile + counted vmcnt ------
// T1 bijective XCD swizzle, T2 g(r)-chunk swizzle (unchanged from verified
// round-1 layout), T3+T4 phase interleave with vmcnt(4) once per K-tile
// (ring-4 LDS slots, STAGE issued 2 tiles ahead), T5 setprio around MFMA.
// acc * 2^-8 = cosine (inputs pre-scaled by 16).
__global__ __launch_bounds__(512, 2) void gemm5_kernel(
        const uint8_t* __restrict__ An, const uint8_t* __restrict__ Wn8,
        float* __restrict__ rowsum) {
    __shared__ uint8_t As[4][16384];   // 4 slots x 256 rows x 64 B
    __shared__ uint8_t Bs[4][16384];
    __shared__ float red[256];

    // bijective XCD swizzle (m204): nwg=1108, q=138, r=4
    int orig = blockIdx.x;
    int xcd = orig & 7, idx = orig >> 3;
    const int q = (4 * NCT2) >> 3, r = (4 * NCT2) & 7;
    int wgid = (xcd < r ? xcd * (q + 1) : r * (q + 1) + (xcd - r) * q) + idx;
    int mtile = wgid & 3, ctile = wgid >> 2;

    int tid = threadIdx.x, lane = tid & 63, wv = tid >> 6;
    if (tid < 256) red[tid] = 0.0f;

    // staging: each of 8 waves covers 16 rows x 64 B per part; 4 parts/K-tile
    int sr = lane >> 2;
    int gsw = (sr & 3) ^ ((sr >> 2) & 3);
    int ck = ((lane & 3) ^ gsw) * 16;            // swizzled source chunk offset
    const uint8_t* aG0 = An + (size_t)(mtile * 256 +       wv * 16 + sr) * DIM + ck;
    const uint8_t* aG1 = An + (size_t)(mtile * 256 + 128 + wv * 16 + sr) * DIM + ck;
    int cb0 = min(ctile * 256 +       wv * 16 + sr, NCLS - 1);
    int cb1 = min(ctile * 256 + 128 + wv * 16 + sr, NCLS - 1);
    const uint8_t* bG0 = Wn8 + (size_t)cb0 * DIM + ck;
    const uint8_t* bG1 = Wn8 + (size_t)cb1 * DIM + ck;

    // wave -> 128x64 output sub-tile
    int wm = (wv >> 2) * 128, wn = (wv & 3) * 64;
    int fr = lane & 15, fq = lane >> 4;
    int fh = fq >> 1, fl = (fq & 1) * 8;
    int gf = ((fr & 3) ^ ((fr >> 2) & 3)) * 16;
    int offS0 = fr * 64 + ((fh * 16) ^ gf) + fl;          // k-slice s=0
    int offS1 = fr * 64 + (((2 + fh) * 16) ^ gf) + fl;    // k-slice s=1

    long af[8][2], bf[4][2];
    floatx4 acc[8][4] = {};

#define GLL(gp, lp) __builtin_amdgcn_global_load_lds( \
        (const __attribute__((address_space(1))) unsigned int*)(gp), \
        (__attribute__((address_space(3))) unsigned int*)(lp), 16, 0, 0)

#define STAGE(tt) do { \
        uint8_t* _al = &As[(tt) & 3][0] + wv * 1024; \
        uint8_t* _bl = &Bs[(tt) & 3][0] + wv * 1024; \
        int _kc = (tt) * 64; \
        GLL(aG0 + _kc, _al); \
        GLL(aG1 + _kc, _al + 8192); \
        GLL(bG0 + _kc, _bl); \
        GLL(bG1 + _kc, _bl + 8192); \
    } while (0)

#define MFMA16(mlo, nlo) do { \
        _Pragma("unroll") \
        for (int s = 0; s < 2; ++s) \
            _Pragma("unroll") \
            for (int m = 0; m < 4; ++m) \
                _Pragma("unroll") \
                for (int n = 0; n < 2; ++n) \
                    acc[(mlo) + m][(nlo) + n] = \
                        __builtin_amdgcn_mfma_f32_16x16x32_fp8_fp8( \
                            af[(mlo) + m][s], bf[(nlo) + n][s], \
                            acc[(mlo) + m][(nlo) + n], 0, 0, 0); \
    } while (0)

#define FENCE asm volatile("" ::: "memory")
#define BAR   __builtin_amdgcn_s_barrier()
#define PRIO1 __builtin_amdgcn_s_setprio(1)
#define PRIO0 __builtin_amdgcn_s_setprio(0)

    // prologue: tiles 0,1 in flight; wait tile 0, keep tile 1 flying
    STAGE(0);
    STAGE(1);
    asm volatile("s_waitcnt vmcnt(4)" ::: "memory");
    BAR;

    #pragma unroll
    for (int kt = 0; kt < 8; ++kt) {
        const uint8_t* Ab = &As[kt & 3][0];
        const uint8_t* Bb = &Bs[kt & 3][0];
        // ---- P0: stage t+2 | read A[m0-3], B[n0-1] | MFMA q00
        if (kt + 2 < 8) STAGE(kt + 2);
        #pragma unroll
        for (int m = 0; m < 4; ++m) {
            af[m][0] = *(const long*)(Ab + (wm + m * 16) * 64 + offS0);
            af[m][1] = *(const long*)(Ab + (wm + m * 16) * 64 + offS1);
        }
        #pragma unroll
        for (int n = 0; n < 2; ++n) {
            bf[n][0] = *(const long*)(Bb + (wn + n * 16) * 64 + offS0);
            bf[n][1] = *(const long*)(Bb + (wn + n * 16) * 64 + offS1);
        }
        FENCE; BAR;
        PRIO1; MFMA16(0, 0); PRIO0;
        FENCE; BAR;
        // ---- P1: read A[m4-7] | MFMA q10
        #pragma unroll
        for (int m = 4; m < 8; ++m) {
            af[m][0] = *(const long*)(Ab + (wm + m * 16) * 64 + offS0);
            af[m][1] = *(const long*)(Ab + (wm + m * 16) * 64 + offS1);
        }
        FENCE; BAR;
        PRIO1; MFMA16(4, 0); PRIO0;
        FENCE; BAR;
        // ---- P2: read B[n2-3] | MFMA q01
        #pragma unroll
        for (int n = 2; n < 4; ++n) {
            bf[n][0] = *(const long*)(Bb + (wn + n * 16) * 64 + offS0);
            bf[n][1] = *(const long*)(Bb + (wn + n * 16) * 64 + offS1);
        }
        FENCE; BAR;
        PRIO1; MFMA16(0, 2); PRIO0;
        FENCE; BAR;
        // ---- P3: counted wait for next tile's loads | MFMA q11
        if (kt < 6)       asm volatile("s_waitcnt vmcnt(4)" ::: "memory");
        else if (kt == 6) asm volatile("s_waitcnt vmcnt(0)" ::: "memory");
        BAR;
        PRIO1; MFMA16(4, 2); PRIO0;
        FENCE; BAR;
    }

#undef GLL
#undef STAGE
#undef MFMA16
#undef FENCE
#undef BAR
#undef PRIO1
#undef PRIO0

    // epilogue: cosine = acc/256; exp(64c - 64); reduce per row
    const float CLIPC = 0.99999950f;  // cos(0.001)
    const float ISCL  = 1.0f / 256.0f;
    int colbase = ctile * 256 + wn + fr;
    #pragma unroll
    for (int m = 0; m < 8; ++m) {
        #pragma unroll
        for (int reg = 0; reg < 4; ++reg) {
            float s = 0.0f;
            #pragma unroll
            for (int n = 0; n < 4; ++n) {
                int col = colbase + n * 16;
                float c = acc[m][n][reg] * ISCL;
                c = fminf(fmaxf(c, -CLIPC), CLIPC);
                float term = __expf(64.0f * c - 64.0f);
                s += (col < NCLS) ? term : 0.0f;
            }
            s += __shfl_xor(s, 1); s += __shfl_xor(s, 2);
            s += __shfl_xor(s, 4); s += __shfl_xor(s, 8);
            if (fr == 0) atomicAdd(&red[wm + m * 16 + fq * 4 + reg], s);
        }
    }
    __syncthreads();
    if (tid < 256) atomicAdd(rowsum + mtile * 256 + tid, red[tid]);
}

// --- kernel 3: fused batch-stats + margin correction + log + mean ----------
__global__ __launch_bounds__(1024) void finalize_kernel(
        const float* __restrict__ rowsum, const float* __restrict__ coslab,
        const float* __restrict__ rownorm, float* __restrict__ out) {
    __shared__ float sd[1024];
    int t = threadIdx.x;
    float v = fminf(fmaxf(rownorm[t], 0.001f), 100.0f);   // safe_norms
    sd[t] = v; __syncthreads();
    for (int s = 512; s > 0; s >>= 1) { if (t < s) sd[t] += sd[t + s]; __syncthreads(); }
    float mean = sd[0] * (1.0f / 1024.0f);
    __syncthreads();
    float d = v - mean;
    sd[t] = d * d; __syncthreads();
    for (int s = 512; s > 0; s >>= 1) { if (t < s) sd[t] += sd[t + s]; __syncthreads(); }
    float stdv = sqrtf(sd[0] * (1.0f / 1023.0f));         // ddof=1
    float ms = d / (stdv + 0.001f) * 0.333f;
    ms = fminf(fmaxf(ms, -1.0f), 1.0f);
    float g_ang = -0.4f * ms;
    float g_add =  0.4f + 0.4f * ms;
    const float CLIPC = 0.99999950f;
    const float PI = 3.14159265358979323846f;
    float cl  = fminf(fmaxf(coslab[t], -1.0f), 1.0f);
    float cne = fminf(fmaxf(cl, -CLIPC), CLIPC);
    float logit_non = 64.0f * cne;                        // ~ what the GEMM summed
    float theta = acosf(cl);
    float tm = fminf(fmaxf(theta + g_ang, 0.001f), PI - 0.001f);
    float logit_true = (__cosf(tm) - g_add) * 64.0f;
    float ssum = rowsum[t] - __expf(logit_non - 64.0f) + __expf(logit_true - 64.0f);
    float loss = logf(ssum) + 64.0f - logit_true;
    __syncthreads();
    sd[t] = loss; __syncthreads();
    for (int s = 512; s > 0; s >>= 1) { if (t < s) sd[t] += sd[t + s]; __syncthreads(); }
    if (t == 0) out[0] = sd[0] * (1.0f / 1024.0f);
}

extern "C" void kernel_launch(void* const* d_in, const int* in_sizes, int n_in,
                              void* d_out, int out_size, void* d_ws, size_t ws_size,
                              hipStream_t stream) {
    const float* x      = (const float*)d_in[0];
    const int*   labels = (const int*)d_in[1];
    const float* W      = (const float*)d_in[2];
    float* out = (float*)d_out;
    char* ws = (char*)d_ws;

    // workspace layout (~36.8 MB)
    const size_t SZ_WN8 = 36212736;   // 70722*512 fp8, 4K-aligned pad
    const size_t SZ_AN  = 524288;     // 1024*512 fp8
    uint8_t* Wn8 = (uint8_t*)ws;
    uint8_t* An  = (uint8_t*)(ws + SZ_WN8);
    float* rownorm = (float*)(ws + SZ_WN8 + SZ_AN);
    float* rowsum  = rownorm + 1024;
    float* coslab  = rowsum + 1024;

    int wblocks = (NCLS + 3) / 4;     // wave-per-row W normalization
    prep_kernel<<<NROWS / 4 + wblocks, 256, 0, stream>>>(
        x, W, labels, An, Wn8, rownorm, coslab, rowsum);
    gemm5_kernel<<<4 * NCT2, 512, 0, stream>>>(An, Wn8, rowsum);
    finalize_kernel<<<1, 1024, 0, stream>>>(rowsum, coslab, rownorm, out);
}

// Round 3
// 299.336 us; speedup vs baseline: 1.0579x; 1.0579x over previous
//
#include <hip/hip_runtime.h>
#include <hip/hip_bf16.h>
#include <stdint.h>

#define DIM 512
#define NROWS 1024
#define NCLS 70722
// 277 c-tiles of 256 cols; 32 c-groups: cgrp<21 own 9 tiles, else 8 (stride-32 walk)

typedef float floatx4 __attribute__((ext_vector_type(4)));

// pack 4 floats -> 4 OCP e4m3 bytes (HW cvt, RNE+sat)
__device__ __forceinline__ unsigned pk4_fp8(float a, float b, float c, float d) {
    unsigned v = 0;
    v = __builtin_amdgcn_cvt_pk_fp8_f32(a, b, v, false);  // low 16 bits
    v = __builtin_amdgcn_cvt_pk_fp8_f32(c, d, v, true);   // high 16 bits
    return v;
}

__device__ __forceinline__ float wave_reduce_sum(float s) {
    #pragma unroll
    for (int m = 1; m < 64; m <<= 1) s += __shfl_xor(s, m);
    return s;
}

// --- kernel 1: fused prep (unchanged from round-1, proven) ------------------
__global__ __launch_bounds__(256) void prep_kernel(
        const float* __restrict__ x, const float* __restrict__ W,
        const int* __restrict__ labels,
        uint8_t* __restrict__ An, uint8_t* __restrict__ Wn8,
        float* __restrict__ rownorm, float* __restrict__ coslab,
        float* __restrict__ rowsum) {
    int b = blockIdx.x;
    int wv = threadIdx.x >> 6, lane = threadIdx.x & 63;
    if (b < NROWS / 4) {
        if (threadIdx.x < 4) rowsum[b * 4 + threadIdx.x] = 0.0f;
        int row = b * 4 + wv;
        int lab = labels[row];
        const float4* xs = (const float4*)(x + (size_t)row * DIM);
        const float4* ws = (const float4*)(W + (size_t)lab * DIM);
        float4 xa = xs[lane * 2], xb = xs[lane * 2 + 1];
        float4 wa = ws[lane * 2], wb = ws[lane * 2 + 1];
        float dxx = xa.x*xa.x + xa.y*xa.y + xa.z*xa.z + xa.w*xa.w
                  + xb.x*xb.x + xb.y*xb.y + xb.z*xb.z + xb.w*xb.w;
        float dww = wa.x*wa.x + wa.y*wa.y + wa.z*wa.z + wa.w*wa.w
                  + wb.x*wb.x + wb.y*wb.y + wb.z*wb.z + wb.w*wb.w;
        float dxw = xa.x*wa.x + xa.y*wa.y + xa.z*wa.z + xa.w*wa.w
                  + xb.x*wb.x + xb.y*wb.y + xb.z*wb.z + xb.w*wb.w;
        dxx = wave_reduce_sum(dxx);
        dww = wave_reduce_sum(dww);
        dxw = wave_reduce_sum(dxw);
        float norm = sqrtf(dxx);
        float s16 = 16.0f / fmaxf(norm, 1e-12f);
        uint2 p;
        p.x = pk4_fp8(xa.x*s16, xa.y*s16, xa.z*s16, xa.w*s16);
        p.y = pk4_fp8(xb.x*s16, xb.y*s16, xb.z*s16, xb.w*s16);
        *(uint2*)(An + (size_t)row * DIM + lane * 8) = p;
        if (lane == 0) {
            rownorm[row] = norm;
            coslab[row]  = dxw / (fmaxf(norm, 1e-12f) * fmaxf(sqrtf(dww), 1e-12f));
        }
    } else {
        int c = (b - NROWS / 4) * 4 + wv;
        if (c < NCLS) {
            const float4* src = (const float4*)(W + (size_t)c * DIM);
            float4 va = src[lane * 2], vb = src[lane * 2 + 1];
            float ss = va.x*va.x + va.y*va.y + va.z*va.z + va.w*va.w
                     + vb.x*vb.x + vb.y*vb.y + vb.z*vb.z + vb.w*vb.w;
            ss = wave_reduce_sum(ss);
            float s16 = 16.0f / fmaxf(sqrtf(ss), 1e-12f);
            uint2 p;
            p.x = pk4_fp8(va.x*s16, va.y*s16, va.z*s16, va.w*s16);
            p.y = pk4_fp8(vb.x*s16, vb.y*s16, vb.z*s16, vb.w*s16);
            *(uint2*)(Wn8 + (size_t)c * DIM + lane * 8) = p;
        }
    }
}

// --- kernel 2: persistent-A fp8 GEMM -----------------------------------------
// 256 blocks (8 mgrp x 32 cgrp), 512 thr. A[128][512] staged ONCE (64KB LDS,
// chunk swizzle phys = c ^ (r&7) over 32 chunks/row). Per c-tile (256 cols):
// 4 K-stages of BK=128, B dbuf 2x32KB (8 chunks/row, same XOR swizzle).
// Proven round-1 sync: STAGE next -> vmcnt(4) -> bar -> 64 MFMA -> bar.
// XCD: blocks sharing cgrp have b%8 = cgrp%8 -> same XCD L2 for B panels.
__global__ __launch_bounds__(512, 2) void gemm6_kernel(
        const uint8_t* __restrict__ An, const uint8_t* __restrict__ Wn8,
        float* __restrict__ rowsum) {
    __shared__ uint8_t Asm[128 * 512];     // 64 KB
    __shared__ uint8_t Bsm[2][256 * 128];  // 2 x 32 KB
    __shared__ float red[128];

    int b = blockIdx.x;
    int mgrp = b >> 5, cgrp = b & 31;
    int tid = threadIdx.x, lane = tid & 63, wv = tid >> 6;
    if (tid < 128) red[tid] = 0.0f;

    // A staging lane constants: thread t -> row i*16 + (t>>5), phys chunk t&31
    int arow = tid >> 5;                        // 0..15
    int aq = ((tid & 31) ^ (arow & 7)) * 16;    // pre-swizzled source chunk
    const uint8_t* aGb = An + (size_t)(mgrp * 128 + arow) * DIM + aq;

    // B staging lane constants: per issue, lane -> row i*8 + (lane>>3), phys lane&7
    int brow = lane >> 3;                       // 0..7
    int ckB = ((lane & 7) ^ brow) * 16;         // pre-swizzled source chunk

    int wm = (wv >> 2) * 64, wn = (wv & 3) * 64;   // wave = 64M x 64C
    int fr = lane & 15, fq = lane >> 4;
    int fh = fq >> 1, fl = (fq & 1) * 8;

    const floatx4 vzero = {0.0f, 0.0f, 0.0f, 0.0f};
    floatx4 acc[4][4] = {};

#define GLL(gp, lp) __builtin_amdgcn_global_load_lds( \
        (const __attribute__((address_space(1))) unsigned int*)(gp), \
        (__attribute__((address_space(3))) unsigned int*)(lp), 16, 0, 0)
#define BAR  __builtin_amdgcn_s_barrier()
#define FEN  asm volatile("" ::: "memory")

    // ---- A panel: 8 issues, staged once, never rewritten
    #pragma unroll
    for (int i = 0; i < 8; ++i)
        GLL(aGb + i * 8192, Asm + i * 8192 + wv * 1024);

    // ---- B base pointers for first c-tile
    const uint8_t *bp0, *bp1, *bp2, *bp3;
    {
        int cb = cgrp * 256 + wv * 32 + brow;
        bp0 = Wn8 + (size_t)min(cb,      NCLS - 1) * DIM + ckB;
        bp1 = Wn8 + (size_t)min(cb + 8,  NCLS - 1) * DIM + ckB;
        bp2 = Wn8 + (size_t)min(cb + 16, NCLS - 1) * DIM + ckB;
        bp3 = Wn8 + (size_t)min(cb + 24, NCLS - 1) * DIM + ckB;
    }

#define STAGE_B(slot, kb) do { \
        uint8_t* _d = Bsm[slot] + wv * 4096; \
        GLL(bp0 + (kb), _d); \
        GLL(bp1 + (kb), _d + 1024); \
        GLL(bp2 + (kb), _d + 2048); \
        GLL(bp3 + (kb), _d + 3072); } while (0)

#define COMPUTE(slot, cA) do { \
        long af[4][4], bg[4][4]; \
        _Pragma("unroll") \
        for (int m = 0; m < 4; ++m) { \
            int R = wm + m * 16 + fr; \
            const uint8_t* rp = Asm + R * 512 + fl; \
            _Pragma("unroll") \
            for (int ks = 0; ks < 4; ++ks) { \
                int cch = (cA) + ks * 2 + fh; \
                af[m][ks] = *(const long*)(rp + ((cch ^ (R & 7)) * 16)); \
            } \
        } \
        _Pragma("unroll") \
        for (int n = 0; n < 4; ++n) { \
            int R = wn + n * 16 + fr; \
            const uint8_t* rp = Bsm[slot] + R * 128 + fl; \
            _Pragma("unroll") \
            for (int ks = 0; ks < 4; ++ks) { \
                int cch = ks * 2 + fh; \
                bg[n][ks] = *(const long*)(rp + ((cch ^ (R & 7)) * 16)); \
            } \
        } \
        _Pragma("unroll") \
        for (int ks = 0; ks < 4; ++ks) \
            _Pragma("unroll") \
            for (int m = 0; m < 4; ++m) \
                _Pragma("unroll") \
                for (int n = 0; n < 4; ++n) \
                    acc[m][n] = __builtin_amdgcn_mfma_f32_16x16x32_fp8_fp8( \
                        af[m][ks], bg[n][ks], acc[m][n], 0, 0, 0); \
    } while (0)

    STAGE_B(0, 0);    // stage (ct=0, k=0); first wait covers A + this

    int nct = (cgrp < 21) ? 9 : 8;
    int c = cgrp;
    for (int ct = 0; ct < nct; ++ct) {
        // ---- k=0: prefetch k=1 | compute slot0 (K 0..127)
        STAGE_B(1, 128);
        asm volatile("s_waitcnt vmcnt(4)" ::: "memory");
        BAR;
        COMPUTE(0, 0);
        FEN; BAR;
        // ---- k=1: prefetch k=2 | compute slot1 (K 128..255)
        STAGE_B(0, 256);
        asm volatile("s_waitcnt vmcnt(4)" ::: "memory");
        BAR;
        COMPUTE(1, 8);
        FEN; BAR;
        // ---- k=2: prefetch k=3 | compute slot0 (K 256..383)
        STAGE_B(1, 384);
        asm volatile("s_waitcnt vmcnt(4)" ::: "memory");
        BAR;
        COMPUTE(0, 16);
        FEN; BAR;
        // ---- k=3: prefetch next c-tile's k=0 | compute slot1 (K 384..511)
        if (ct != nct - 1) {
            int cb = (c + 32) * 256 + wv * 32 + brow;
            bp0 = Wn8 + (size_t)min(cb,      NCLS - 1) * DIM + ckB;
            bp1 = Wn8 + (size_t)min(cb + 8,  NCLS - 1) * DIM + ckB;
            bp2 = Wn8 + (size_t)min(cb + 16, NCLS - 1) * DIM + ckB;
            bp3 = Wn8 + (size_t)min(cb + 24, NCLS - 1) * DIM + ckB;
            STAGE_B(0, 0);
            asm volatile("s_waitcnt vmcnt(4)" ::: "memory");
        } else {
            asm volatile("s_waitcnt vmcnt(0)" ::: "memory");
        }
        BAR;
        COMPUTE(1, 24);
        FEN; BAR;

        // ---- epilogue for c-tile c: exp + row-reduce (hides next-B latency)
        {
            const float CLIPC = 0.99999950f;  // cos(0.001)
            const float ISCL  = 1.0f / 256.0f;
            int colbase = c * 256 + wn + fr;
            #pragma unroll
            for (int m = 0; m < 4; ++m) {
                #pragma unroll
                for (int reg = 0; reg < 4; ++reg) {
                    float s = 0.0f;
                    #pragma unroll
                    for (int n = 0; n < 4; ++n) {
                        int col = colbase + n * 16;
                        float cc = acc[m][n][reg] * ISCL;
                        cc = fminf(fmaxf(cc, -CLIPC), CLIPC);
                        float term = __expf(64.0f * cc - 64.0f);
                        s += (col < NCLS) ? term : 0.0f;
                    }
                    s += __shfl_xor(s, 1); s += __shfl_xor(s, 2);
                    s += __shfl_xor(s, 4); s += __shfl_xor(s, 8);
                    if (fr == 0) atomicAdd(&red[wm + m * 16 + fq * 4 + reg], s);
                }
            }
            #pragma unroll
            for (int m = 0; m < 4; ++m)
                #pragma unroll
                for (int n = 0; n < 4; ++n)
                    acc[m][n] = vzero;
        }
        c += 32;
    }

#undef GLL
#undef STAGE_B
#undef COMPUTE
#undef BAR
#undef FEN

    __syncthreads();
    if (tid < 128) atomicAdd(rowsum + mgrp * 128 + tid, red[tid]);
}

// --- kernel 3: fused batch-stats + margin correction + log + mean ----------
__global__ __launch_bounds__(1024) void finalize_kernel(
        const float* __restrict__ rowsum, const float* __restrict__ coslab,
        const float* __restrict__ rownorm, float* __restrict__ out) {
    __shared__ float sd[1024];
    int t = threadIdx.x;
    float v = fminf(fmaxf(rownorm[t], 0.001f), 100.0f);   // safe_norms
    sd[t] = v; __syncthreads();
    for (int s = 512; s > 0; s >>= 1) { if (t < s) sd[t] += sd[t + s]; __syncthreads(); }
    float mean = sd[0] * (1.0f / 1024.0f);
    __syncthreads();
    float d = v - mean;
    sd[t] = d * d; __syncthreads();
    for (int s = 512; s > 0; s >>= 1) { if (t < s) sd[t] += sd[t + s]; __syncthreads(); }
    float stdv = sqrtf(sd[0] * (1.0f / 1023.0f));         // ddof=1
    float ms = d / (stdv + 0.001f) * 0.333f;
    ms = fminf(fmaxf(ms, -1.0f), 1.0f);
    float g_ang = -0.4f * ms;
    float g_add =  0.4f + 0.4f * ms;
    const float CLIPC = 0.99999950f;
    const float PI = 3.14159265358979323846f;
    float cl  = fminf(fmaxf(coslab[t], -1.0f), 1.0f);
    float cne = fminf(fmaxf(cl, -CLIPC), CLIPC);
    float logit_non = 64.0f * cne;                        // ~ what the GEMM summed
    float theta = acosf(cl);
    float tm = fminf(fmaxf(theta + g_ang, 0.001f), PI - 0.001f);
    float logit_true = (__cosf(tm) - g_add) * 64.0f;
    float ssum = rowsum[t] - __expf(logit_non - 64.0f) + __expf(logit_true - 64.0f);
    float loss = logf(ssum) + 64.0f - logit_true;
    __syncthreads();
    sd[t] = loss; __syncthreads();
    for (int s = 512; s > 0; s >>= 1) { if (t < s) sd[t] += sd[t + s]; __syncthreads(); }
    if (t == 0) out[0] = sd[0] * (1.0f / 1024.0f);
}

extern "C" void kernel_launch(void* const* d_in, const int* in_sizes, int n_in,
                              void* d_out, int out_size, void* d_ws, size_t ws_size,
                              hipStream_t stream) {
    const float* x      = (const float*)d_in[0];
    const int*   labels = (const int*)d_in[1];
    const float* W      = (const float*)d_in[2];
    float* out = (float*)d_out;
    char* ws = (char*)d_ws;

    // workspace layout (~36.8 MB)
    const size_t SZ_WN8 = 36212736;   // 70722*512 fp8, 4K-aligned pad
    const size_t SZ_AN  = 524288;     // 1024*512 fp8
    uint8_t* Wn8 = (uint8_t*)ws;
    uint8_t* An  = (uint8_t*)(ws + SZ_WN8);
    float* rownorm = (float*)(ws + SZ_WN8 + SZ_AN);
    float* rowsum  = rownorm + 1024;
    float* coslab  = rowsum + 1024;

    int wblocks = (NCLS + 3) / 4;     // wave-per-row W normalization
    prep_kernel<<<NROWS / 4 + wblocks, 256, 0, stream>>>(
        x, W, labels, An, Wn8, rownorm, coslab, rowsum);
    gemm6_kernel<<<256, 512, 0, stream>>>(An, Wn8, rowsum);
    finalize_kernel<<<1, 1024, 0, stream>>>(rowsum, coslab, rownorm, out);
}

// Round 4
// 292.086 us; speedup vs baseline: 1.0842x; 1.0248x over previous
//
#include <hip/hip_runtime.h>
#include <hip/hip_bf16.h>
#include <stdint.h>

#define DIM 512
#define NROWS 1024
#define NCLS 70722
// 277 c-tiles of 256 cols; 32 c-groups: cgrp<21 own 9 tiles, else 8 (stride-32 walk)

typedef float floatx4 __attribute__((ext_vector_type(4)));

// pack 4 floats -> 4 OCP e4m3 bytes (HW cvt, RNE+sat)
__device__ __forceinline__ unsigned pk4_fp8(float a, float b, float c, float d) {
    unsigned v = 0;
    v = __builtin_amdgcn_cvt_pk_fp8_f32(a, b, v, false);  // low 16 bits
    v = __builtin_amdgcn_cvt_pk_fp8_f32(c, d, v, true);   // high 16 bits
    return v;
}

__device__ __forceinline__ float wave_reduce_sum(float s) {
    #pragma unroll
    for (int m = 1; m < 64; m <<= 1) s += __shfl_xor(s, m);
    return s;
}

// --- kernel 1: fused prep (unchanged, proven) --------------------------------
__global__ __launch_bounds__(256) void prep_kernel(
        const float* __restrict__ x, const float* __restrict__ W,
        const int* __restrict__ labels,
        uint8_t* __restrict__ An, uint8_t* __restrict__ Wn8,
        float* __restrict__ rownorm, float* __restrict__ coslab,
        float* __restrict__ rowsum) {
    int b = blockIdx.x;
    int wv = threadIdx.x >> 6, lane = threadIdx.x & 63;
    if (b < NROWS / 4) {
        if (threadIdx.x < 4) rowsum[b * 4 + threadIdx.x] = 0.0f;
        int row = b * 4 + wv;
        int lab = labels[row];
        const float4* xs = (const float4*)(x + (size_t)row * DIM);
        const float4* ws = (const float4*)(W + (size_t)lab * DIM);
        float4 xa = xs[lane * 2], xb = xs[lane * 2 + 1];
        float4 wa = ws[lane * 2], wb = ws[lane * 2 + 1];
        float dxx = xa.x*xa.x + xa.y*xa.y + xa.z*xa.z + xa.w*xa.w
                  + xb.x*xb.x + xb.y*xb.y + xb.z*xb.z + xb.w*xb.w;
        float dww = wa.x*wa.x + wa.y*wa.y + wa.z*wa.z + wa.w*wa.w
                  + wb.x*wb.x + wb.y*wb.y + wb.z*wb.z + wb.w*wb.w;
        float dxw = xa.x*wa.x + xa.y*wa.y + xa.z*wa.z + xa.w*wa.w
                  + xb.x*wb.x + xb.y*wb.y + xb.z*wb.z + xb.w*wb.w;
        dxx = wave_reduce_sum(dxx);
        dww = wave_reduce_sum(dww);
        dxw = wave_reduce_sum(dxw);
        float norm = sqrtf(dxx);
        float s16 = 16.0f / fmaxf(norm, 1e-12f);
        uint2 p;
        p.x = pk4_fp8(xa.x*s16, xa.y*s16, xa.z*s16, xa.w*s16);
        p.y = pk4_fp8(xb.x*s16, xb.y*s16, xb.z*s16, xb.w*s16);
        *(uint2*)(An + (size_t)row * DIM + lane * 8) = p;
        if (lane == 0) {
            rownorm[row] = norm;
            coslab[row]  = dxw / (fmaxf(norm, 1e-12f) * fmaxf(sqrtf(dww), 1e-12f));
        }
    } else {
        int c = (b - NROWS / 4) * 4 + wv;
        if (c < NCLS) {
            const float4* src = (const float4*)(W + (size_t)c * DIM);
            float4 va = src[lane * 2], vb = src[lane * 2 + 1];
            float ss = va.x*va.x + va.y*va.y + va.z*va.z + va.w*va.w
                     + vb.x*vb.x + vb.y*vb.y + vb.z*vb.z + vb.w*vb.w;
            ss = wave_reduce_sum(ss);
            float s16 = 16.0f / fmaxf(sqrtf(ss), 1e-12f);
            uint2 p;
            p.x = pk4_fp8(va.x*s16, va.y*s16, va.z*s16, va.w*s16);
            p.y = pk4_fp8(vb.x*s16, vb.y*s16, vb.z*s16, vb.w*s16);
            *(uint2*)(Wn8 + (size_t)c * DIM + lane * 8) = p;
        }
    }
}

// --- kernel 2: persistent-A-in-REGISTERS fp8 GEMM ----------------------------
// 256 blocks (8 mgrp x 32 cgrp), 512 thr. A[128][512] staged to LDS once, then
// each wave's A fragments for ALL of K live in af[4][16] (128 VGPR) across the
// whole c-tile walk. Steady-state K-stage = 16 B ds_reads + 64 MFMA only.
// B dbuf 2x32KB, chunk swizzle phys = c ^ (r&7); round-3's proven sync:
// STAGE next -> vmcnt(4) -> bar -> COMPUTE -> bar. Running exp-sum in srun.
__global__ __launch_bounds__(512, 2) void gemm7_kernel(
        const uint8_t* __restrict__ An, const uint8_t* __restrict__ Wn8,
        float* __restrict__ rowsum) {
    __shared__ uint8_t Asm[128 * 512];     // 64 KB (used once, prologue)
    __shared__ uint8_t Bsm[2][256 * 128];  // 2 x 32 KB
    __shared__ float red[128];

    int b = blockIdx.x;
    int mgrp = b >> 5, cgrp = b & 31;
    int tid = threadIdx.x, lane = tid & 63, wv = tid >> 6;
    if (tid < 128) red[tid] = 0.0f;

    // A staging: thread t -> row (t>>5) (+16/issue), phys chunk t&31, src chunk ^(row&7)
    int arow = tid >> 5;
    int aq = ((tid & 31) ^ (arow & 7)) * 16;
    const uint8_t* aGb = An + (size_t)(mgrp * 128 + arow) * DIM + aq;

    // B staging: lane -> row lane>>3 (+8/issue), phys chunk lane&7, src ^row
    int brow = lane >> 3;
    int ckB = ((lane & 7) ^ brow) * 16;

    int wm = (wv >> 2) * 64, wn = (wv & 3) * 64;   // wave = 64M x 64C
    int fr = lane & 15, fq = lane >> 4;
    int fh = fq >> 1, fl = (fq & 1) * 8;

    const floatx4 vzero = {0.0f, 0.0f, 0.0f, 0.0f};
    floatx4 acc[4][4] = {};
    float srun[4][4] = {};
    long af[4][16];

#define GLL(gp, lp) __builtin_amdgcn_global_load_lds( \
        (const __attribute__((address_space(1))) unsigned int*)(gp), \
        (__attribute__((address_space(3))) unsigned int*)(lp), 16, 0, 0)
#define BAR  __builtin_amdgcn_s_barrier()
#define FEN  asm volatile("" ::: "memory")

    // ---- prologue: stage A panel (8 issues) + first B tile
    #pragma unroll
    for (int i = 0; i < 8; ++i)
        GLL(aGb + i * 8192, Asm + i * 8192 + wv * 1024);

    const uint8_t *bp0, *bp1, *bp2, *bp3;
    {
        int cb = cgrp * 256 + wv * 32 + brow;
        bp0 = Wn8 + (size_t)min(cb,      NCLS - 1) * DIM + ckB;
        bp1 = Wn8 + (size_t)min(cb + 8,  NCLS - 1) * DIM + ckB;
        bp2 = Wn8 + (size_t)min(cb + 16, NCLS - 1) * DIM + ckB;
        bp3 = Wn8 + (size_t)min(cb + 24, NCLS - 1) * DIM + ckB;
    }

#define STAGE_B(slot, kb) do { \
        uint8_t* _d = Bsm[slot] + wv * 4096; \
        GLL(bp0 + (kb), _d); \
        GLL(bp1 + (kb), _d + 1024); \
        GLL(bp2 + (kb), _d + 2048); \
        GLL(bp3 + (kb), _d + 3072); } while (0)

    STAGE_B(0, 0);
    asm volatile("s_waitcnt vmcnt(4)" ::: "memory");   // A landed (8 oldest)
    BAR;

    // ---- fill A fragments for ALL of K into registers (once per block)
    #pragma unroll
    for (int m = 0; m < 4; ++m) {
        int R = wm + m * 16 + fr;
        const uint8_t* rp = Asm + R * 512 + fl;
        #pragma unroll
        for (int ksl = 0; ksl < 16; ++ksl)
            af[m][ksl] = *(const long*)(rp + (((2 * ksl + fh) ^ (R & 7)) * 16));
    }

// COMPUTE: B-only ds_reads (per-n to cap bg live range) + 64 MFMA
#define COMPUTE(slot, KSB) do { \
        _Pragma("unroll") \
        for (int n = 0; n < 4; ++n) { \
            int R = wn + n * 16 + fr; \
            const uint8_t* rp = Bsm[slot] + R * 128 + fl; \
            long bg[4]; \
            _Pragma("unroll") \
            for (int ks = 0; ks < 4; ++ks) \
                bg[ks] = *(const long*)(rp + (((ks * 2 + fh) ^ (R & 7)) * 16)); \
            _Pragma("unroll") \
            for (int ks = 0; ks < 4; ++ks) \
                _Pragma("unroll") \
                for (int m = 0; m < 4; ++m) \
                    acc[m][n] = __builtin_amdgcn_mfma_f32_16x16x32_fp8_fp8( \
                        af[m][(KSB) + ks], bg[ks], acc[m][n], 0, 0, 0); \
        } \
    } while (0)

    int nct = (cgrp < 21) ? 9 : 8;
    int c = cgrp;
    for (int ct = 0; ct < nct; ++ct) {
        // ---- k0: prefetch k1 | compute slot0 (K 0..127)
        STAGE_B(1, 128);
        asm volatile("s_waitcnt vmcnt(4)" ::: "memory");
        BAR;
        __builtin_amdgcn_s_setprio(1); COMPUTE(0, 0);  __builtin_amdgcn_s_setprio(0);
        FEN; BAR;
        // ---- k1: prefetch k2 | compute slot1 (K 128..255)
        STAGE_B(0, 256);
        asm volatile("s_waitcnt vmcnt(4)" ::: "memory");
        BAR;
        __builtin_amdgcn_s_setprio(1); COMPUTE(1, 4);  __builtin_amdgcn_s_setprio(0);
        FEN; BAR;
        // ---- k2: prefetch k3 | compute slot0 (K 256..383)
        STAGE_B(1, 384);
        asm volatile("s_waitcnt vmcnt(4)" ::: "memory");
        BAR;
        __builtin_amdgcn_s_setprio(1); COMPUTE(0, 8);  __builtin_amdgcn_s_setprio(0);
        FEN; BAR;
        // ---- k3: prefetch next c-tile's k0 | compute slot1 (K 384..511)
        if (ct != nct - 1) {
            int cb = (c + 32) * 256 + wv * 32 + brow;
            bp0 = Wn8 + (size_t)min(cb,      NCLS - 1) * DIM + ckB;
            bp1 = Wn8 + (size_t)min(cb + 8,  NCLS - 1) * DIM + ckB;
            bp2 = Wn8 + (size_t)min(cb + 16, NCLS - 1) * DIM + ckB;
            bp3 = Wn8 + (size_t)min(cb + 24, NCLS - 1) * DIM + ckB;
            STAGE_B(0, 0);
            asm volatile("s_waitcnt vmcnt(4)" ::: "memory");
        } else {
            asm volatile("s_waitcnt vmcnt(0)" ::: "memory");
        }
        BAR;
        __builtin_amdgcn_s_setprio(1); COMPUTE(1, 12); __builtin_amdgcn_s_setprio(0);
        FEN; BAR;

        // ---- per-tile: exp into running per-lane sums (no shuffles here)
        {
            const float CLIPC = 0.99999950f;  // cos(0.001)
            const float ISCL  = 1.0f / 256.0f;
            int colbase = c * 256 + wn + fr;
            #pragma unroll
            for (int m = 0; m < 4; ++m) {
                #pragma unroll
                for (int reg = 0; reg < 4; ++reg) {
                    float s = 0.0f;
                    #pragma unroll
                    for (int n = 0; n < 4; ++n) {
                        int col = colbase + n * 16;
                        float cc = acc[m][n][reg] * ISCL;
                        cc = fminf(fmaxf(cc, -CLIPC), CLIPC);
                        float term = __expf(64.0f * cc - 64.0f);
                        s += (col < NCLS) ? term : 0.0f;
                    }
                    srun[m][reg] += s;
                }
            }
            #pragma unroll
            for (int m = 0; m < 4; ++m)
                #pragma unroll
                for (int n = 0; n < 4; ++n)
                    acc[m][n] = vzero;
        }
        c += 32;
    }

#undef GLL
#undef STAGE_B
#undef COMPUTE
#undef BAR
#undef FEN

    // ---- final reduction: once per block
    #pragma unroll
    for (int m = 0; m < 4; ++m) {
        #pragma unroll
        for (int reg = 0; reg < 4; ++reg) {
            float s = srun[m][reg];
            s += __shfl_xor(s, 1); s += __shfl_xor(s, 2);
            s += __shfl_xor(s, 4); s += __shfl_xor(s, 8);
            if (fr == 0) atomicAdd(&red[wm + m * 16 + fq * 4 + reg], s);
        }
    }
    __syncthreads();
    if (tid < 128) atomicAdd(rowsum + mgrp * 128 + tid, red[tid]);
}

// --- kernel 3: batch-stats + margin + log + mean, wave-shuffle reduced ------
__global__ __launch_bounds__(1024) void finalize_kernel(
        const float* __restrict__ rowsum, const float* __restrict__ coslab,
        const float* __restrict__ rownorm, float* __restrict__ out) {
    __shared__ float part[16];
    __shared__ float bc[2];
    int t = threadIdx.x, lane = t & 63, w = t >> 6;
    float v = fminf(fmaxf(rownorm[t], 0.001f), 100.0f);   // safe_norms

    float s = wave_reduce_sum(v);
    if (lane == 0) part[w] = s;
    __syncthreads();
    if (t < 64) {
        float p = (lane < 16) ? part[lane] : 0.0f;
        p = wave_reduce_sum(p);
        if (lane == 0) bc[0] = p * (1.0f / 1024.0f);
    }
    __syncthreads();
    float mean = bc[0];
    float d = v - mean;

    s = wave_reduce_sum(d * d);
    if (lane == 0) part[w] = s;
    __syncthreads();
    if (t < 64) {
        float p = (lane < 16) ? part[lane] : 0.0f;
        p = wave_reduce_sum(p);
        if (lane == 0) bc[1] = sqrtf(p * (1.0f / 1023.0f));  // ddof=1
    }
    __syncthreads();
    float stdv = bc[1];

    float ms = d / (stdv + 0.001f) * 0.333f;
    ms = fminf(fmaxf(ms, -1.0f), 1.0f);
    float g_ang = -0.4f * ms;
    float g_add =  0.4f + 0.4f * ms;
    const float CLIPC = 0.99999950f;
    const float PI = 3.14159265358979323846f;
    float cl  = fminf(fmaxf(coslab[t], -1.0f), 1.0f);
    float cne = fminf(fmaxf(cl, -CLIPC), CLIPC);
    float logit_non = 64.0f * cne;                        // ~ what the GEMM summed
    float theta = acosf(cl);
    float tm = fminf(fmaxf(theta + g_ang, 0.001f), PI - 0.001f);
    float logit_true = (__cosf(tm) - g_add) * 64.0f;
    float ssum = rowsum[t] - __expf(logit_non - 64.0f) + __expf(logit_true - 64.0f);
    float loss = logf(ssum) + 64.0f - logit_true;

    s = wave_reduce_sum(loss);
    if (lane == 0) part[w] = s;
    __syncthreads();
    if (t < 64) {
        float p = (lane < 16) ? part[lane] : 0.0f;
        p = wave_reduce_sum(p);
        if (lane == 0) out[0] = p * (1.0f / 1024.0f);
    }
}

extern "C" void kernel_launch(void* const* d_in, const int* in_sizes, int n_in,
                              void* d_out, int out_size, void* d_ws, size_t ws_size,
                              hipStream_t stream) {
    const float* x      = (const float*)d_in[0];
    const int*   labels = (const int*)d_in[1];
    const float* W      = (const float*)d_in[2];
    float* out = (float*)d_out;
    char* ws = (char*)d_ws;

    // workspace layout (~36.8 MB)
    const size_t SZ_WN8 = 36212736;   // 70722*512 fp8, 4K-aligned pad
    const size_t SZ_AN  = 524288;     // 1024*512 fp8
    uint8_t* Wn8 = (uint8_t*)ws;
    uint8_t* An  = (uint8_t*)(ws + SZ_WN8);
    float* rownorm = (float*)(ws + SZ_WN8 + SZ_AN);
    float* rowsum  = rownorm + 1024;
    float* coslab  = rowsum + 1024;

    int wblocks = (NCLS + 3) / 4;     // wave-per-row W normalization
    prep_kernel<<<NROWS / 4 + wblocks, 256, 0, stream>>>(
        x, W, labels, An, Wn8, rownorm, coslab, rowsum);
    gemm7_kernel<<<256, 512, 0, stream>>>(An, Wn8, rowsum);
    finalize_kernel<<<1, 1024, 0, stream>>>(rowsum, coslab, rownorm, out);
}